// Round 10
// baseline (788.075 us; speedup 1.0000x reference)
//
#include <hip/hip_runtime.h>

#define N_TOK 4096
#define DM 256
#define NH 8
#define DK 32
#define SEGMAX 768   // fast-path cap; actual segments ~256±16 (16 uniform buckets)

using u16 = unsigned short;
using u32 = unsigned int;
using i64 = long long;
typedef float f32x4 __attribute__((ext_vector_type(4)));   // native vec for nontemporal

__device__ __forceinline__ float bf2f(u16 u){ return __uint_as_float(((u32)u) << 16); }
__device__ __forceinline__ u16 f2bf(float f){
    u32 x = __float_as_uint(f);
    x += 0x7fffu + ((x >> 16) & 1u);
    return (u16)(x >> 16);
}

// ---- per-query segment bounds (batch sorted; int32 or int64 probed) ----
__global__ __launch_bounds__(256)
void bounds_kernel(const void* __restrict__ batch_q, const void* __restrict__ batch_kv,
                   int2* __restrict__ bounds)
{
    int q = blockIdx.x * 256 + threadIdx.x;
    const int* kv32 = (const int*)batch_kv;
    const i64* kv64 = (const i64*)batch_kv;
    bool is64 = (kv32[N_TOK - 1] == 0);
    int s = is64 ? (int)((const i64*)batch_q)[q] : ((const int*)batch_q)[q];
    int lo = 0, hi = N_TOK;
    while (lo < hi){ int m = (lo + hi) >> 1; int v = is64 ? (int)kv64[m] : kv32[m]; if (v < s) lo = m + 1; else hi = m; }
    int lo2 = lo, hi2 = N_TOK;
    while (lo2 < hi2){ int m = (lo2 + hi2) >> 1; int v = is64 ? (int)kv64[m] : kv32[m]; if (v <= s) lo2 = m + 1; else hi2 = m; }
    bounds[q] = make_int2(lo, lo2);
}

// out[r][c] = sum_d x[r][d] * W[c][d] + b[c]
template<int OUT_BF16>
__global__ __launch_bounds__(256)
void proj_kernel(const float* __restrict__ x, const float* __restrict__ W,
                 const float* __restrict__ bias, void* __restrict__ outv)
{
    const int ROWS = 16;
    int row0 = blockIdx.x * ROWS;
    int c = threadIdx.x;
    float acc[ROWS];
    float bv = bias[c];
#pragma unroll
    for (int r = 0; r < ROWS; ++r) acc[r] = bv;
    const float4* Wv = (const float4*)(W + (size_t)c * DM);
    for (int i = 0; i < DM / 4; ++i){
        float4 w = Wv[i];
        int d0 = i * 4;
#pragma unroll
        for (int r = 0; r < ROWS; ++r){
            const float* xr = x + (size_t)(row0 + r) * DM + d0;
            acc[r] += xr[0] * w.x + xr[1] * w.y + xr[2] * w.z + xr[3] * w.w;
        }
    }
#pragma unroll
    for (int r = 0; r < ROWS; ++r){
        size_t idx = (size_t)(row0 + r) * DM + c;
        if (OUT_BF16) ((u16*)outv)[idx] = f2bf(acc[r]);
        else          ((float*)outv)[idx] = acc[r];
    }
}

// Fused K+V projection from x_kv; writes bf16 K and V workspace tensors.
__global__ __launch_bounds__(256)
void proj_kv_kernel(const float* __restrict__ x, const float* __restrict__ Wk,
                    const float* __restrict__ bk, const float* __restrict__ Wv,
                    const float* __restrict__ bv, u16* __restrict__ Kp,
                    u16* __restrict__ Vp)
{
    const int ROWS = 16;
    int row0 = blockIdx.x * ROWS;
    int c = threadIdx.x;
    float acck[ROWS], accv[ROWS];
    float bkv = bk[c], bvv = bv[c];
#pragma unroll
    for (int r = 0; r < ROWS; ++r){ acck[r] = bkv; accv[r] = bvv; }
    const float4* Wk4 = (const float4*)(Wk + (size_t)c * DM);
    const float4* Wv4 = (const float4*)(Wv + (size_t)c * DM);
    for (int i = 0; i < DM / 4; ++i){
        float4 wk = Wk4[i];
        float4 wv = Wv4[i];
        int d0 = i * 4;
#pragma unroll
        for (int r = 0; r < ROWS; ++r){
            const float* xr = x + (size_t)(row0 + r) * DM + d0;
            float x0 = xr[0], x1 = xr[1], x2 = xr[2], x3 = xr[3];
            acck[r] += x0 * wk.x + x1 * wk.y + x2 * wk.z + x3 * wk.w;
            accv[r] += x0 * wv.x + x1 * wv.y + x2 * wv.z + x3 * wv.w;
        }
    }
#pragma unroll
    for (int r = 0; r < ROWS; ++r){
        size_t idx = (size_t)(row0 + r) * DM + c;
        Kp[idx] = f2bf(acck[r]);
        Vp[idx] = f2bf(accv[r]);
    }
}

// One block per query q, ALL 8 heads. Fast path (seg<=SEGMAX): thread
// (h=tid>>5, j=tid&31); each head's 32 lanes live in ONE wave -> width-32
// shuffle softmax, per-head LDS slice private to its wave, ZERO block
// barriers, no trailing vmcnt-drain barrier. All attn stores nontemporal
// (no L2-line mixing; keeps K/V resident). Slow path: R9-style per-head
// sequential with barriers (any seg size; never triggers for this input).
__global__ __launch_bounds__(256)
void attn_fused(const float* __restrict__ Q, const u16* __restrict__ K,
                const u16* __restrict__ V, const int2* __restrict__ bounds,
                float* __restrict__ attn, float* __restrict__ O)
{
    __shared__ float sc[NH][SEGMAX];   // 24 KB; slow path reuses as flat[6144]
    __shared__ float red[8];
    __shared__ float Osh[DK];

    int q = blockIdx.x, tid = threadIdx.x;
    int2 b = bounds[q];
    const int lo = b.x, hi = b.y, seg = hi - lo;
    const float scale = 0.17677669529663687f;   // 1/sqrt(32)

    if (seg <= SEGMAX){
        int h = tid >> 5, j = tid & 31;
        // Q slice into registers (redundant across j lanes; L1 broadcast)
        float qf[32];
        const float4* qp = (const float4*)(Q + (size_t)q * DM + h * DK);
#pragma unroll
        for (int i = 0; i < 8; ++i){
            float4 v = qp[i];
            qf[4*i] = v.x; qf[4*i+1] = v.y; qf[4*i+2] = v.z; qf[4*i+3] = v.w;
        }
        // pass 1: raw scores -> LDS, online (m,l) per lane
        float m = -1e30f, l = 0.f;
        for (int k = lo + j; k < hi; k += 32){
            const uint4* kr = (const uint4*)(K + (size_t)k * DM + h * DK);
            float dot = 0.f;
#pragma unroll
            for (int i = 0; i < 4; ++i){
                uint4 p = kr[i];
                dot += qf[i*8+0]*bf2f((u16)p.x) + qf[i*8+1]*bf2f((u16)(p.x>>16));
                dot += qf[i*8+2]*bf2f((u16)p.y) + qf[i*8+3]*bf2f((u16)(p.y>>16));
                dot += qf[i*8+4]*bf2f((u16)p.z) + qf[i*8+5]*bf2f((u16)(p.z>>16));
                dot += qf[i*8+6]*bf2f((u16)p.w) + qf[i*8+7]*bf2f((u16)(p.w>>16));
            }
            dot *= scale;
            sc[h][k - lo] = dot;
            float nm = fmaxf(m, dot);
            l = l * __expf(m - nm) + __expf(dot - nm);
            m = nm;
        }
        // head-local butterfly over 32 lanes (masks <=16 stay in head group)
#pragma unroll
        for (int off = 16; off; off >>= 1){
            float mo = __shfl_xor(m, off, 64);
            float lx = __shfl_xor(l, off, 64);
            float nm = fmaxf(m, mo);
            l = l * __expf(m - nm) + lx * __expf(mo - nm);
            m = nm;
        }
        float inv = (l > 0.f) ? (1.f / l) : 0.f;

        // pass 2: probs -> LDS (for PV) + NT scalar stores to attn row
        float* arow = attn + ((size_t)h * N_TOK + q) * N_TOK;
        for (int k = lo + j; k < hi; k += 32){
            float p = __expf(sc[h][k - lo] - m) * inv;
            sc[h][k - lo] = p;
            __builtin_nontemporal_store(p, &arow[k]);
        }
        // zeros outside [lo,hi): full quads NT f32x4, remainders NT scalar
        int lo4 = lo & ~3, hi4 = (hi + 3) & ~3;
        f32x4 z4 = {0.f, 0.f, 0.f, 0.f};
        for (int t = j; t < (lo4 >> 2); t += 32)
            __builtin_nontemporal_store(z4, (f32x4*)arow + t);
        for (int k = lo4 + j; k < lo; k += 32)
            __builtin_nontemporal_store(0.f, &arow[k]);
        for (int k = hi + j; k < hi4; k += 32)
            __builtin_nontemporal_store(0.f, &arow[k]);
        for (int t = (hi4 >> 2) + j; t < N_TOK / 4; t += 32)
            __builtin_nontemporal_store(z4, (f32x4*)arow + t);

        // PV: (h, d2=j&15, g=j>>4); sc[h] is wave-private -> no barrier
        int d2 = j & 15, g = j >> 4;
        float p0 = 0.f, p1 = 0.f;
        for (int k = lo + g; k < hi; k += 2){
            u32 pv = *(const u32*)(V + (size_t)k * DM + h * DK + 2 * d2);
            float p = sc[h][k - lo];
            p0 += p * bf2f((u16)pv);
            p1 += p * bf2f((u16)(pv >> 16));
        }
        p0 += __shfl_xor(p0, 16, 64);
        p1 += __shfl_xor(p1, 16, 64);
        if (g == 0){
            float2 o2 = make_float2(p0, p1);   // probs already normalized
            *(float2*)(O + (size_t)q * DM + h * DK + 2 * d2) = o2;
        }
    } else {
        // ---- generic slow path: heads sequential, block-wide (R9 logic) ----
        float* scf = &sc[0][0];                // 6144 floats >= any seg (<=4096)
        for (int h = 0; h < NH; ++h){
            const float* qrow = Q + (size_t)q * DM + h * DK;
            float lmax = -1e30f;
            for (int k = lo + tid; k < hi; k += 256){
                const uint4* kr = (const uint4*)(K + (size_t)k * DM + h * DK);
                float dot = 0.f;
#pragma unroll
                for (int i = 0; i < 4; ++i){
                    uint4 p = kr[i];
                    dot += qrow[i*8+0]*bf2f((u16)p.x) + qrow[i*8+1]*bf2f((u16)(p.x>>16));
                    dot += qrow[i*8+2]*bf2f((u16)p.y) + qrow[i*8+3]*bf2f((u16)(p.y>>16));
                    dot += qrow[i*8+4]*bf2f((u16)p.z) + qrow[i*8+5]*bf2f((u16)(p.z>>16));
                    dot += qrow[i*8+6]*bf2f((u16)p.w) + qrow[i*8+7]*bf2f((u16)(p.w>>16));
                }
                dot *= scale;
                scf[k - lo] = dot;
                lmax = fmaxf(lmax, dot);
            }
#pragma unroll
            for (int off = 32; off; off >>= 1) lmax = fmaxf(lmax, __shfl_xor(lmax, off, 64));
            if ((tid & 63) == 0) red[tid >> 6] = lmax;
            __syncthreads();
            float mm = fmaxf(fmaxf(red[0], red[1]), fmaxf(red[2], red[3]));
            float lsum = 0.f;
            for (int k = lo + tid; k < hi; k += 256){
                float p = __expf(scf[k - lo] - mm);
                scf[k - lo] = p;
                lsum += p;
            }
#pragma unroll
            for (int off = 32; off; off >>= 1) lsum += __shfl_xor(lsum, off, 64);
            if ((tid & 63) == 0) red[4 + (tid >> 6)] = lsum;
            if (tid < DK) Osh[tid] = 0.f;
            __syncthreads();
            float s = red[4] + red[5] + red[6] + red[7];
            float inv = (s > 0.f) ? (1.f / s) : 0.f;
            float* arow = attn + ((size_t)h * N_TOK + q) * N_TOK;
            for (int t = tid; t < N_TOK / 4; t += 256){
                int k0 = 4 * t;
                f32x4 w;
                w.x = (k0+0 >= lo && k0+0 < hi) ? scf[k0+0-lo]*inv : 0.f;
                w.y = (k0+1 >= lo && k0+1 < hi) ? scf[k0+1-lo]*inv : 0.f;
                w.z = (k0+2 >= lo && k0+2 < hi) ? scf[k0+2-lo]*inv : 0.f;
                w.w = (k0+3 >= lo && k0+3 < hi) ? scf[k0+3-lo]*inv : 0.f;
                __builtin_nontemporal_store(w, (f32x4*)arow + t);
            }
            int d2 = tid & 15, g = tid >> 4;
            float p0 = 0.f, p1 = 0.f;
            for (int k = lo + g; k < hi; k += 16){
                u32 pv = *(const u32*)(V + (size_t)k * DM + h * DK + 2 * d2);
                float p = scf[k - lo];
                p0 += p * bf2f((u16)pv);
                p1 += p * bf2f((u16)(pv >> 16));
            }
            p0 += __shfl_xor(p0, 16, 64); p0 += __shfl_xor(p0, 32, 64);
            p1 += __shfl_xor(p1, 16, 64); p1 += __shfl_xor(p1, 32, 64);
            if ((tid & 63) < 16){
                atomicAdd(&Osh[2*d2 + 0], p0);
                atomicAdd(&Osh[2*d2 + 1], p1);
            }
            __syncthreads();
            if (tid < DK) O[(size_t)q * DM + h * DK + tid] = Osh[tid] * inv;
            __syncthreads();   // scf/red reuse next head
        }
    }
}

extern "C" void kernel_launch(void* const* d_in, const int* in_sizes, int n_in,
                              void* d_out, int out_size, void* d_ws, size_t ws_size,
                              hipStream_t stream)
{
    const float* x_q  = (const float*)d_in[0];
    const float* x_kv = (const float*)d_in[1];
    const void* batch_q  = d_in[2];
    const void* batch_kv = d_in[3];
    const float* Wq = (const float*)d_in[4];
    const float* bq = (const float*)d_in[5];
    const float* Wk = (const float*)d_in[6];
    const float* bk = (const float*)d_in[7];
    const float* Wv = (const float*)d_in[8];
    const float* bv = (const float*)d_in[9];
    const float* Wo = (const float*)d_in[10];
    const float* bo = (const float*)d_in[11];

    char* ws = (char*)d_ws;
    float* Q  = (float*)ws;                                 // 4 MB fp32
    u16*   Kp = (u16*)(ws + (size_t)4 * 1024 * 1024);       // 2 MB bf16
    u16*   Vp = (u16*)(ws + (size_t)6 * 1024 * 1024);       // 2 MB bf16
    float* O  = (float*)(ws + (size_t)8 * 1024 * 1024);     // 4 MB fp32
    int2* bounds = (int2*)(ws + (size_t)12 * 1024 * 1024);  // 32 KB

    float* out  = (float*)d_out;                            // [4096,256] fp32
    float* attn = out + (size_t)N_TOK * DM;                 // [8,4096,4096] fp32

    bounds_kernel<<<N_TOK / 256, 256, 0, stream>>>(batch_q, batch_kv, bounds);
    proj_kernel<0><<<N_TOK/16, 256, 0, stream>>>(x_q,  Wq, bq, Q);
    proj_kv_kernel<<<N_TOK/16, 256, 0, stream>>>(x_kv, Wk, bk, Wv, bv, Kp, Vp);
    attn_fused<<<N_TOK, 256, 0, stream>>>(Q, Kp, Vp, bounds, attn, O);
    proj_kernel<0><<<N_TOK/16, 256, 0, stream>>>((const float*)O, Wo, bo, out);
}